// Round 6
// baseline (178.484 us; speedup 1.0000x reference)
//
#include <hip/hip_runtime.h>
#include <hip/hip_fp16.h>

#define N_NODES 50000
#define N_EDGES 800000
#define D 64
#define LN_EPS 1e-5f
#define CAP 48           // padded CSR slots/node; P(Poisson(16) > 48) ~ 1e-12
#define NR 8             // node ranges == XCD count
#define RSPAN ((N_NODES + NR - 1) / NR)          // 6250 nodes/range
#define ECHUNKS 512
#define EPC ((N_EDGES + ECHUNKS - 1) / ECHUNKS)  // 1563 edges/chunk

// ws layout: cnt (N int) | xh (N*D half, 16B-aligned) | ssrc (N*CAP ushort)

// block = (range r = bid&7, edge chunk = bid>>3); range r only touched by
// bid%8==r blocks (round-robin -> same XCD); its 600 KB ssrc slice is
// L2-resident -> write combining on the random 2B bucket stores.
__global__ void fill_k(const int* __restrict__ src, const int* __restrict__ dst,
                       int* __restrict__ cnt, unsigned short* __restrict__ ssrc) {
    int r = blockIdx.x & (NR - 1);
    int chunk = blockIdx.x >> 3;
    int lo = r * RSPAN;
    int hi = lo + RSPAN; if (hi > N_NODES) hi = N_NODES;
    int ebeg = chunk * EPC;
    int eend = ebeg + EPC; if (eend > N_EDGES) eend = N_EDGES;
    for (int e = ebeg + threadIdx.x; e < eend; e += 256) {
        int t = dst[e];
        if (t >= lo && t < hi) {
            int pos = atomicAdd(&cnt[t], 1);
            if (pos < CAP) ssrc[(size_t)t * CAP + pos] = (unsigned short)src[e];
        }
    }
}

// xh[i] = fp16( rsqrt(deg_i+1) * x[i] )  -- the dinv_src scaling, pre-applied
__global__ void prep_k(const float* __restrict__ x, const int* __restrict__ cnt,
                       __half* __restrict__ xh) {
    int i = blockIdx.x * 256 + threadIdx.x;      // one float4 -> 4 halves
    if (i < N_NODES * D / 4) {
        int row = i >> 4;
        float di = rsqrtf((float)cnt[row] + 1.0f);
        float4 v = ((const float4*)x)[i];
        __half2* o = (__half2*)xh + (size_t)i * 2;
        o[0] = __floats2half2_rn(di * v.x, di * v.y);
        o[1] = __floats2half2_rn(di * v.z, di * v.w);
    }
}

// Fused: gather-aggregate u-tile (64 nodes) into LDS, then u@W GEMM with
// W column in VGPRs, then h = x + dinv*(u@W) + b, LayerNorm, ReLU, store.
// z = dinv_i*(u@W) where u = sum_edges xh[src] + xh[i]  (linearity of @W).
__global__ __launch_bounds__(256) void fused_k(
        const float* __restrict__ x, const __half* __restrict__ xh,
        const int* __restrict__ cnt, const unsigned short* __restrict__ ssrc,
        const float* __restrict__ W, const float* __restrict__ b,
        const float* __restrict__ gamma, const float* __restrict__ beta,
        float* __restrict__ out) {
    __shared__ float y[D * D];                   // 16 KB u-tile
    int tid = threadIdx.x;
    int lane = tid & 63;
    int wv = tid >> 6;                           // wave: rows wv*16..wv*16+15
    int row0 = blockIdx.x * 64;

    // ---- phase 1: aggregate. 8 edges in flight: sub=lane/8, c8=lane%8 ----
    int sub = lane >> 3;
    int c8 = lane & 7;
    for (int rr = 0; rr < 16; ++rr) {
        int row = row0 + wv * 16 + rr;
        float4 a0 = make_float4(0.f, 0.f, 0.f, 0.f);
        float4 a1 = make_float4(0.f, 0.f, 0.f, 0.f);
        if (row < N_NODES) {
            int dc = cnt[row];
            int deg = dc < CAP ? dc : CAP;
            size_t base = (size_t)row * CAP;
            if (sub == 0) {                      // self-loop term xh[row]
                float4 raw = *(const float4*)(xh + (size_t)row * D + c8 * 8);
                const __half2* hp = (const __half2*)&raw;
                float2 p0 = __half22float2(hp[0]), p1 = __half22float2(hp[1]);
                float2 p2 = __half22float2(hp[2]), p3 = __half22float2(hp[3]);
                a0.x += p0.x; a0.y += p0.y; a0.z += p1.x; a0.w += p1.y;
                a1.x += p2.x; a1.y += p2.y; a1.z += p3.x; a1.w += p3.y;
            }
            for (int j = sub; j < deg; j += 8) {
                int s = ssrc[base + j];
                float4 raw = *(const float4*)(xh + (size_t)s * D + c8 * 8);
                const __half2* hp = (const __half2*)&raw;
                float2 p0 = __half22float2(hp[0]), p1 = __half22float2(hp[1]);
                float2 p2 = __half22float2(hp[2]), p3 = __half22float2(hp[3]);
                a0.x += p0.x; a0.y += p0.y; a0.z += p1.x; a0.w += p1.y;
                a1.x += p2.x; a1.y += p2.y; a1.z += p3.x; a1.w += p3.y;
            }
        }
#pragma unroll
        for (int o = 8; o < 64; o <<= 1) {
            a0.x += __shfl_xor(a0.x, o, 64); a0.y += __shfl_xor(a0.y, o, 64);
            a0.z += __shfl_xor(a0.z, o, 64); a0.w += __shfl_xor(a0.w, o, 64);
            a1.x += __shfl_xor(a1.x, o, 64); a1.y += __shfl_xor(a1.y, o, 64);
            a1.z += __shfl_xor(a1.z, o, 64); a1.w += __shfl_xor(a1.w, o, 64);
        }
        if (sub == 0) {                          // lanes 0..7 hold the row
            float* yr = y + (wv * 16 + rr) * D + c8 * 8;
            *(float4*)yr = a0;
            *(float4*)(yr + 4) = a1;
        }
    }

    // W column for this lane (fills the barrier wait; L2-hot across blocks)
    float wcol[D];
#pragma unroll
    for (int k = 0; k < D; ++k) wcol[k] = W[k * D + lane];
    float bl = b[lane], gl = gamma[lane], el = beta[lane];
    __syncthreads();

    // ---- phase 2: GEMM + skip + LN + ReLU, 16 rows per wave ----
    for (int rr = 0; rr < 16; ++rr) {
        int r = wv * 16 + rr;
        int grow = row0 + r;
        if (grow >= N_NODES) break;
        const float4* yr = (const float4*)(y + r * D);
        float acc = 0.f;
#pragma unroll
        for (int k4 = 0; k4 < 16; ++k4) {
            float4 v = yr[k4];                   // wave-uniform addr: broadcast
            acc += v.x * wcol[k4 * 4 + 0];
            acc += v.y * wcol[k4 * 4 + 1];
            acc += v.z * wcol[k4 * 4 + 2];
            acc += v.w * wcol[k4 * 4 + 3];
        }
        float di = rsqrtf((float)cnt[grow] + 1.0f);
        float h = x[(size_t)grow * D + lane] + di * acc + bl;
        float s_ = h;
#pragma unroll
        for (int o = 1; o < 64; o <<= 1) s_ += __shfl_xor(s_, o, 64);
        float mu = s_ * (1.0f / D);
        float d = h - mu;
        float v_ = d * d;
#pragma unroll
        for (int o = 1; o < 64; o <<= 1) v_ += __shfl_xor(v_, o, 64);
        float rstd = rsqrtf(v_ * (1.0f / D) + LN_EPS);
        out[(size_t)grow * D + lane] = fmaxf(d * rstd * gl + el, 0.f);
    }
}

extern "C" void kernel_launch(void* const* d_in, const int* in_sizes, int n_in,
                              void* d_out, int out_size, void* d_ws, size_t ws_size,
                              hipStream_t stream) {
    const float* x     = (const float*)d_in[0];
    const int*   ei    = (const int*)d_in[1];
    const float* W     = (const float*)d_in[2];
    const float* b     = (const float*)d_in[3];
    const float* gamma = (const float*)d_in[4];
    const float* beta  = (const float*)d_in[5];
    float* out = (float*)d_out;

    const int* src = ei;
    const int* dst = ei + N_EDGES;

    int*            cnt  = (int*)d_ws;                       // N ints
    __half*         xh   = (__half*)(cnt + N_NODES);         // N*D halves, 16B-aligned
    unsigned short* ssrc = (unsigned short*)(xh + (size_t)N_NODES * D); // N*CAP ushort

    hipMemsetAsync(cnt, 0, N_NODES * sizeof(int), stream);
    fill_k<<<NR * ECHUNKS, 256, 0, stream>>>(src, dst, cnt, ssrc);
    prep_k<<<(N_NODES * D / 4 + 255) / 256, 256, 0, stream>>>(x, cnt, xh);
    fused_k<<<(N_NODES + 63) / 64, 256, 0, stream>>>(x, xh, cnt, ssrc, W, b, gamma, beta, out);
}

// Round 7
// 162.062 us; speedup vs baseline: 1.1013x; 1.1013x over previous
//
#include <hip/hip_runtime.h>
#include <hip/hip_fp16.h>

#define N_NODES 50000
#define N_EDGES 800000
#define D 64
#define LN_EPS 1e-5f
#define CAP 48           // padded CSR slots/node; P(Poisson(16) > 48) ~ 1e-12
#define NR 8             // node ranges == XCD count
#define RSPAN ((N_NODES + NR - 1) / NR)          // 6250 nodes/range
#define ECHUNKS 512
#define EPC ((N_EDGES + ECHUNKS - 1) / ECHUNKS)  // 1563 edges/chunk

typedef unsigned short u16;

// ws layout (all 16B-aligned):
//   cnt:  N int            (200000 B)
//   xs:   N*D half         (6.4 MB)   xs = fp16(dinv * (x@W))
//   usrc: E u16            (1.6 MB)
//   udst: E u16            (1.6 MB)
//   ssrc: N*CAP u16        (4.8 MB)

// compress edge streams to u16 AND zero cnt (grid covers E/4 threads > N)
__global__ void prep_edges_k(const int* __restrict__ src, const int* __restrict__ dst,
                             u16* __restrict__ usrc, u16* __restrict__ udst,
                             int* __restrict__ cnt) {
    int gid = blockIdx.x * 256 + threadIdx.x;
    if (gid < N_NODES) cnt[gid] = 0;
    if (gid < N_EDGES / 4) {
        int4 s = ((const int4*)src)[gid];
        int4 d = ((const int4*)dst)[gid];
        ((uint2*)usrc)[gid] = make_uint2((unsigned)(u16)s.x | ((unsigned)(u16)s.y << 16),
                                         (unsigned)(u16)s.z | ((unsigned)(u16)s.w << 16));
        ((uint2*)udst)[gid] = make_uint2((unsigned)(u16)d.x | ((unsigned)(u16)d.y << 16),
                                         (unsigned)(u16)d.z | ((unsigned)(u16)d.w << 16));
    }
}

// block = (range r = bid&7, edge chunk = bid>>3); range r only touched by
// bid%8==r blocks (round-robin -> same XCD); its 600 KB ssrc slice is
// L2-resident -> write combining on the random 2B bucket stores.
__global__ void fill_k(const u16* __restrict__ usrc, const u16* __restrict__ udst,
                       int* __restrict__ cnt, u16* __restrict__ ssrc) {
    int r = blockIdx.x & (NR - 1);
    int chunk = blockIdx.x >> 3;
    int lo = r * RSPAN;
    int hi = lo + RSPAN; if (hi > N_NODES) hi = N_NODES;
    int ebeg = chunk * EPC;
    int eend = ebeg + EPC; if (eend > N_EDGES) eend = N_EDGES;
    for (int e = ebeg + threadIdx.x; e < eend; e += 256) {
        int t = udst[e];
        if (t >= lo && t < hi) {
            int pos = atomicAdd(&cnt[t], 1);
            if (pos < CAP) ssrc[(size_t)t * CAP + pos] = usrc[e];
        }
    }
}

// xs[row] = fp16( rsqrt(cnt[row]+1) * (x[row] @ W) )
// W column per lane in 64 VGPRs; x tile in LDS, read via same-address
// float4 broadcasts (conflict-free).
__global__ __launch_bounds__(256) void gemm_xs(const float* __restrict__ x,
                                               const float* __restrict__ W,
                                               const int* __restrict__ cnt,
                                               __half* __restrict__ xs) {
    __shared__ float xlds[D * D];
    int tid = threadIdx.x;
    int row0 = blockIdx.x * 64;

    const float4* xg = (const float4*)(x + (size_t)row0 * D);
    float4* xl4 = (float4*)xlds;
    for (int i = tid; i < D * D / 4; i += 256) {
        int grow = row0 + (i >> 4);            // 16 float4 per row
        xl4[i] = (grow < N_NODES) ? xg[i] : make_float4(0.f, 0.f, 0.f, 0.f);
    }

    int lane = tid & 63;
    float wcol[D];
#pragma unroll
    for (int k = 0; k < D; ++k) wcol[k] = W[k * D + lane];
    __syncthreads();

    int wv = tid >> 6;
    for (int rr = 0; rr < 16; ++rr) {
        int r = wv * 16 + rr;
        int grow = row0 + r;
        if (grow >= N_NODES) break;
        const float4* xr = (const float4*)(xlds + r * D);
        float acc = 0.f;
#pragma unroll
        for (int k4 = 0; k4 < 16; ++k4) {
            float4 xv = xr[k4];
            acc += xv.x * wcol[k4 * 4 + 0];
            acc += xv.y * wcol[k4 * 4 + 1];
            acc += xv.z * wcol[k4 * 4 + 2];
            acc += xv.w * wcol[k4 * 4 + 3];
        }
        float di = rsqrtf((float)cnt[grow] + 1.0f);   // +1 self-loop
        xs[(size_t)grow * D + lane] = __float2half(di * acc);
    }
}

// wave per node, 8 edges in flight: sub = lane/8 picks the edge slot,
// c8 = lane%8 picks an 8-half (16B) column group. Register-prefetched
// ssrc (breaks the ssrc->gather dependency; up to 7 gathers in flight).
// Self-loop folded in as an extra source on sub 0. Fused LN+ReLU.
__global__ void agg_ln_k(const float* __restrict__ x, const __half* __restrict__ xs,
                         const int* __restrict__ cnt, const u16* __restrict__ ssrc,
                         const float* __restrict__ b, const float* __restrict__ gamma,
                         const float* __restrict__ beta, float* __restrict__ out) {
    int row = blockIdx.x * 4 + (threadIdx.x >> 6);
    if (row >= N_NODES) return;
    int lane = threadIdx.x & 63;
    int sub = lane >> 3;        // 0..7
    int c8  = lane & 7;

    int dc = cnt[row];
    int deg = dc < CAP ? dc : CAP;
    size_t base = (size_t)row * CAP;

    // prefetch my ssrc slots (broadcast within each sub-group), then self-loop
    int sv[7];
    int nr = (deg > sub) ? ((deg - sub + 7) >> 3) : 0;   // <= 6
#pragma unroll
    for (int r2 = 0; r2 < 6; ++r2)
        if (r2 < nr) sv[r2] = ssrc[base + sub + (r2 << 3)];
    if (sub == 0) { sv[nr] = row; ++nr; }                // self-loop term

    float4 a0 = make_float4(0.f, 0.f, 0.f, 0.f);
    float4 a1 = make_float4(0.f, 0.f, 0.f, 0.f);
#pragma unroll
    for (int r2 = 0; r2 < 7; ++r2) {
        if (r2 < nr) {
            int s = sv[r2];
            float4 raw = *(const float4*)(xs + (size_t)s * D + c8 * 8);  // 8 halves
            const __half2* hp = (const __half2*)&raw;
            float2 p0 = __half22float2(hp[0]), p1 = __half22float2(hp[1]);
            float2 p2 = __half22float2(hp[2]), p3 = __half22float2(hp[3]);
            a0.x += p0.x; a0.y += p0.y; a0.z += p1.x; a0.w += p1.y;
            a1.x += p2.x; a1.y += p2.y; a1.z += p3.x; a1.w += p3.y;
        }
    }
    // reduce over the 8 subs; afterwards every lane holds full sums for its c8 group
#pragma unroll
    for (int o = 8; o < 64; o <<= 1) {
        a0.x += __shfl_xor(a0.x, o, 64); a0.y += __shfl_xor(a0.y, o, 64);
        a0.z += __shfl_xor(a0.z, o, 64); a0.w += __shfl_xor(a0.w, o, 64);
        a1.x += __shfl_xor(a1.x, o, 64); a1.y += __shfl_xor(a1.y, o, 64);
        a1.z += __shfl_xor(a1.z, o, 64); a1.w += __shfl_xor(a1.w, o, 64);
    }

    float di = rsqrtf((float)dc + 1.0f);

    const float4* xp = (const float4*)(x + (size_t)row * D + c8 * 8);
    float4 x0 = xp[0], x1 = xp[1];
    const float4* bp = (const float4*)(b + c8 * 8);
    float4 b0 = bp[0], b1 = bp[1];

    float h[8];
    h[0] = x0.x + di * a0.x + b0.x;
    h[1] = x0.y + di * a0.y + b0.y;
    h[2] = x0.z + di * a0.z + b0.z;
    h[3] = x0.w + di * a0.w + b0.w;
    h[4] = x1.x + di * a1.x + b1.x;
    h[5] = x1.y + di * a1.y + b1.y;
    h[6] = x1.z + di * a1.z + b1.z;
    h[7] = x1.w + di * a1.w + b1.w;

    // LayerNorm: each column appears once per sub => divisor D*8 = 512
    float s_ = 0.f;
#pragma unroll
    for (int i = 0; i < 8; ++i) s_ += h[i];
#pragma unroll
    for (int o = 1; o < 64; o <<= 1) s_ += __shfl_xor(s_, o, 64);
    float mu = s_ * (1.0f / 512.0f);
    float v_ = 0.f;
    float dd[8];
#pragma unroll
    for (int i = 0; i < 8; ++i) { dd[i] = h[i] - mu; v_ += dd[i] * dd[i]; }
#pragma unroll
    for (int o = 1; o < 64; o <<= 1) v_ += __shfl_xor(v_, o, 64);
    float rstd = rsqrtf(v_ * (1.0f / 512.0f) + LN_EPS);

    if (sub == 0) {
        const float4* gp = (const float4*)(gamma + c8 * 8);
        const float4* ep = (const float4*)(beta + c8 * 8);
        float4 g0 = gp[0], g1 = gp[1];
        float4 e0 = ep[0], e1 = ep[1];
        float4 r0, r1;
        r0.x = fmaxf(dd[0] * rstd * g0.x + e0.x, 0.f);
        r0.y = fmaxf(dd[1] * rstd * g0.y + e0.y, 0.f);
        r0.z = fmaxf(dd[2] * rstd * g0.z + e0.z, 0.f);
        r0.w = fmaxf(dd[3] * rstd * g0.w + e0.w, 0.f);
        r1.x = fmaxf(dd[4] * rstd * g1.x + e1.x, 0.f);
        r1.y = fmaxf(dd[5] * rstd * g1.y + e1.y, 0.f);
        r1.z = fmaxf(dd[6] * rstd * g1.z + e1.z, 0.f);
        r1.w = fmaxf(dd[7] * rstd * g1.w + e1.w, 0.f);
        float4* op = (float4*)(out + (size_t)row * D + c8 * 8);
        op[0] = r0;
        op[1] = r1;
    }
}

extern "C" void kernel_launch(void* const* d_in, const int* in_sizes, int n_in,
                              void* d_out, int out_size, void* d_ws, size_t ws_size,
                              hipStream_t stream) {
    const float* x     = (const float*)d_in[0];
    const int*   ei    = (const int*)d_in[1];
    const float* W     = (const float*)d_in[2];
    const float* b     = (const float*)d_in[3];
    const float* gamma = (const float*)d_in[4];
    const float* beta  = (const float*)d_in[5];
    float* out = (float*)d_out;

    const int* src = ei;
    const int* dst = ei + N_EDGES;

    int*    cnt  = (int*)d_ws;                              // N int
    __half* xs   = (__half*)(cnt + N_NODES);                // N*D half
    u16*    usrc = (u16*)(xs + (size_t)N_NODES * D);        // E u16
    u16*    udst = usrc + N_EDGES;                          // E u16
    u16*    ssrc = udst + N_EDGES;                          // N*CAP u16

    prep_edges_k<<<(N_EDGES / 4 + 255) / 256, 256, 0, stream>>>(src, dst, usrc, udst, cnt);
    fill_k<<<NR * ECHUNKS, 256, 0, stream>>>(usrc, udst, cnt, ssrc);
    gemm_xs<<<(N_NODES + 63) / 64, 256, 0, stream>>>(x, W, cnt, xs);
    agg_ln_k<<<(N_NODES + 3) / 4, 256, 0, stream>>>(x, xs, cnt, ssrc, b, gamma, beta, out);
}